// Round 10
// baseline (195.821 us; speedup 1.0000x reference)
//
#include <hip/hip_runtime.h>
#include <math.h>

#define DIM    1024
#define BATCH  2
#define SEQ    2048
#define NHEAD  16
#define HDIM   64
#define MROWS  (BATCH*SEQ)   // 4096
#define NSPLIT 8             // ktv S-splits

typedef unsigned short u16;
typedef __attribute__((ext_vector_type(8))) short  s16x8;   // 8 bf16 = 4 VGPRs
typedef __attribute__((ext_vector_type(4))) float  f32x4;

__device__ __forceinline__ float bf2f(u16 h) {
    unsigned u = ((unsigned)h) << 16; float f; __builtin_memcpy(&f, &u, 4); return f;
}
__device__ __forceinline__ u16 f2bf(float f) {
    unsigned u; __builtin_memcpy(&u, &f, 4);
    u += 0x7FFFu + ((u >> 16) & 1u);           // round-to-nearest-even
    return (u16)(u >> 16);
}

// async global->LDS DMA, 16B per lane. LDS dest is wave-uniform base + lane*16.
__device__ __forceinline__ void glds16(const u16* g, u16* l) {
    __builtin_amdgcn_global_load_lds(
        (const __attribute__((address_space(1))) void*)g,
        (__attribute__((address_space(3))) void*)l, 16, 0, 0);
}

// ---------------------------------------------------------------------------
// Fused fp32->bf16 pack for x + 5 weights. One launch.
// ---------------------------------------------------------------------------
__global__ __launch_bounds__(256)
void pack_all(const float* __restrict__ x,
              const float* __restrict__ Wq, const float* __restrict__ Wk,
              const float* __restrict__ Wv, const float* __restrict__ W1,
              const float* __restrict__ W2,
              u16* __restrict__ xb, u16* __restrict__ Wqb, u16* __restrict__ Wkb,
              u16* __restrict__ Wvb, u16* __restrict__ W1b, u16* __restrict__ W2b)
{
    const int bid = blockIdx.x;
    const float* src; u16* dst; int i;
    if (bid < 4096) { src = x; dst = xb; i = bid * 256 + threadIdx.x; }
    else {
        const int w = (bid - 4096) >> 10;
        const int lb = (bid - 4096) & 1023;
        src = (w == 0) ? Wq : (w == 1) ? Wk : (w == 2) ? Wv : (w == 3) ? W1 : W2;
        dst = (w == 0) ? Wqb : (w == 1) ? Wkb : (w == 2) ? Wvb : (w == 3) ? W1b : W2b;
        i = lb * 256 + threadIdx.x;
    }
    float4 v = ((const float4*)src)[i];
    ushort4 o = { f2bf(v.x), f2bf(v.y), f2bf(v.z), f2bf(v.w) };
    ((ushort4*)dst)[i] = o;
}

// ---------------------------------------------------------------------------
// GEMM core, tile 128x128, BK=32, 256 thr = 4 waves (2x2), wave tile 64x64.
// T4 counted-vmcnt pipeline: THREE LDS buffers (48 KiB), prefetch depth 2.
// Per iter: wait vmcnt(4) -> s_barrier -> issue tile it+2 -> compute tile it.
// ---------------------------------------------------------------------------
__device__ __forceinline__ void gemm_core_pf128(const u16* __restrict__ Ab,
                                                const u16* __restrict__ Bb,
                                                u16* As, u16* Bs,  // each 3*4096 u16
                                                int tid, f32x4 acc[4][4])
{
    const int w = tid >> 6, l = tid & 63;
    const int wm = (w >> 1) * 64, wn = (w & 1) * 64;
    const int lr = l & 15, kq = l >> 4;

    // staging: wave w covers rows w*16..w*16+15 (4 lanes x 8 u16 per row)
    const int srow = w * 16 + (l >> 2);
    const int scol = (l & 3) * 8;
    const u16* gA = Ab + (size_t)srow * DIM + scol;
    const u16* gB = Bb + (size_t)srow * DIM + scol;
    const int sdst = w * 512;                  // u16 units (wave-uniform)

    // prologue: tile0 -> buf0, tile1 -> buf1 (8 loads in flight)
    glds16(gA,      As + sdst);         glds16(gA + 64 * DIM,      As + 2048 + sdst);
    glds16(gB,      Bs + sdst);         glds16(gB + 64 * DIM,      Bs + 2048 + sdst);
    glds16(gA + 32, As + 4096 + sdst);  glds16(gA + 32 + 64 * DIM, As + 4096 + 2048 + sdst);
    glds16(gB + 32, Bs + 4096 + sdst);  glds16(gB + 32 + 64 * DIM, Bs + 4096 + 2048 + sdst);

    const int NIT = DIM / 32;
    int cur = 0, nxt2 = 2;
    for (int it = 0; it < NIT; ++it) {
        if (it < NIT - 1) { asm volatile("s_waitcnt vmcnt(4)" ::: "memory"); }
        else              { asm volatile("s_waitcnt vmcnt(0)" ::: "memory"); }
        __builtin_amdgcn_s_barrier();
        asm volatile("" ::: "memory");
        if (it + 2 < NIT) {                    // issue tile it+2 -> buf nxt2
            const int k = (it + 2) * 32;
            u16* An = As + nxt2 * 4096 + sdst;
            u16* Bn = Bs + nxt2 * 4096 + sdst;
            glds16(gA + k, An);  glds16(gA + k + 64 * DIM, An + 2048);
            glds16(gB + k, Bn);  glds16(gB + k + 64 * DIM, Bn + 2048);
        }
        const u16* Ac = As + cur * 4096;
        const u16* Bc = Bs + cur * 4096;
        s16x8 af[4], bfr[4];
        #pragma unroll
        for (int i = 0; i < 4; ++i)
            af[i]  = *(const s16x8*)(Ac + (wm + i * 16 + lr) * 32 + kq * 8);
        #pragma unroll
        for (int j = 0; j < 4; ++j)
            bfr[j] = *(const s16x8*)(Bc + (wn + j * 16 + lr) * 32 + kq * 8);
        __builtin_amdgcn_s_setprio(1);
        #pragma unroll
        for (int i = 0; i < 4; ++i)
            #pragma unroll
            for (int j = 0; j < 4; ++j)
                acc[i][j] = __builtin_amdgcn_mfma_f32_16x16x32_bf16(af[i], bfr[j], acc[i][j], 0, 0, 0);
        __builtin_amdgcn_s_setprio(0);
        cur  = (cur  == 2) ? 0 : cur  + 1;
        nxt2 = (nxt2 == 2) ? 0 : nxt2 + 1;
    }
}

// ---------------------------------------------------------------------------
// MLP core, tile 64x128, BK=32, 4 waves (2m x 2n), wave tile 32x64.
// T4 counted-vmcnt, FOUR LDS buffers (48 KiB), prefetch depth 3: per iter
// wait vmcnt(6) (tiles it+1,it+2 stay in flight) -> barrier -> issue tile
// it+3 -> compute tile it. Depth 3 covers ~3 iters of compute (~500 cyc),
// matching L2/HBM latency that depth 2 left exposed (round-8/9 lesson).
// Epilogue drains: vmcnt(3) at it=NIT-2, vmcnt(0) at it=NIT-1.
// WAR: buf[(it+3)&3] last read at iter it-1, complete before iter-it barrier.
// ---------------------------------------------------------------------------
__device__ __forceinline__ void gemm_core_pf64(const u16* __restrict__ Ab,
                                               const u16* __restrict__ Bb,
                                               u16* As /*4*2048*/, u16* Bs /*4*4096*/,
                                               int tid, f32x4 acc[2][4])
{
    const int w  = tid >> 6, l = tid & 63;
    const int wm = (w >> 1) * 32, wn = (w & 1) * 64;
    const int lr = l & 15, kq = l >> 4;

    const int srow = w * 16 + (l >> 2);
    const int scol = (l & 3) * 8;
    const u16* gA = Ab + (size_t)srow * DIM + scol;
    const u16* gB = Bb + (size_t)srow * DIM + scol;
    const int sdst = w * 512;

    // prologue: tiles 0,1,2 -> buf 0,1,2 (9 loads in flight)
    glds16(gA,      As + sdst);
    glds16(gB,      Bs + sdst);        glds16(gB + 64 * DIM,      Bs + 2048 + sdst);
    glds16(gA + 32, As + 2048 + sdst);
    glds16(gB + 32, Bs + 4096 + sdst); glds16(gB + 32 + 64 * DIM, Bs + 4096 + 2048 + sdst);
    glds16(gA + 64, As + 4096 + sdst);
    glds16(gB + 64, Bs + 8192 + sdst); glds16(gB + 64 + 64 * DIM, Bs + 8192 + 2048 + sdst);

    const int NIT = DIM / 32;
    for (int it = 0; it < NIT; ++it) {
        if (it < NIT - 2)       { asm volatile("s_waitcnt vmcnt(6)" ::: "memory"); }
        else if (it == NIT - 2) { asm volatile("s_waitcnt vmcnt(3)" ::: "memory"); }
        else                    { asm volatile("s_waitcnt vmcnt(0)" ::: "memory"); }
        __builtin_amdgcn_s_barrier();
        asm volatile("" ::: "memory");
        if (it + 3 < NIT) {                    // issue tile it+3 -> buf (it+3)&3
            const int k = (it + 3) * 32;
            const int bn = (it + 3) & 3;
            u16* An = As + bn * 2048 + sdst;
            u16* Bn = Bs + bn * 4096 + sdst;
            glds16(gA + k, An);
            glds16(gB + k, Bn);  glds16(gB + k + 64 * DIM, Bn + 2048);
        }
        const u16* Ac = As + (it & 3) * 2048;
        const u16* Bc = Bs + (it & 3) * 4096;
        s16x8 af[2], bfr[4];
        #pragma unroll
        for (int i = 0; i < 2; ++i)
            af[i]  = *(const s16x8*)(Ac + (wm + i * 16 + lr) * 32 + kq * 8);
        #pragma unroll
        for (int j = 0; j < 4; ++j)
            bfr[j] = *(const s16x8*)(Bc + (wn + j * 16 + lr) * 32 + kq * 8);
        __builtin_amdgcn_s_setprio(1);
        #pragma unroll
        for (int i = 0; i < 2; ++i)
            #pragma unroll
            for (int j = 0; j < 4; ++j)
                acc[i][j] = __builtin_amdgcn_mfma_f32_16x16x32_bf16(af[i], bfr[j], acc[i][j], 0, 0, 0);
        __builtin_amdgcn_s_setprio(0);
    }
}

// ---------------------------------------------------------------------------
// Fused QKV projection: grid (32 m-tiles, 24 sel*n-tiles), 256 threads.
// Epilogue: XOR-swizzled LDS bounce -> coalesced dwordx4 stores.
// ---------------------------------------------------------------------------
__global__ __launch_bounds__(256)
void qkv_gemm(const u16* __restrict__ xb,
              const u16* __restrict__ Wq, const u16* __restrict__ Wk, const u16* __restrict__ Wv,
              const float* __restrict__ bq, const float* __restrict__ bk, const float* __restrict__ bv,
              u16* __restrict__ qo, u16* __restrict__ ko, u16* __restrict__ vo)
{
    __shared__ __align__(16) u16 SH[24576];      // loop: As=SH[0..12287], Bs=SH[12288..]
    const int tid = threadIdx.x;
    const int m0  = blockIdx.x * 128;
    const int sel = blockIdx.y >> 3;
    const int n0  = (blockIdx.y & 7) * 128;
    const u16*   B    = (sel == 0) ? Wq : (sel == 1) ? Wk : Wv;
    const float* bias = (sel == 0) ? bq : (sel == 1) ? bk : bv;
    u16*         C    = (sel == 0) ? qo : (sel == 1) ? ko : vo;
    const float scale = (sel == 0) ? 0.125f : 1.0f;

    f32x4 acc[4][4];
    #pragma unroll
    for (int i = 0; i < 4; ++i)
        #pragma unroll
        for (int j = 0; j < 4; ++j) acc[i][j] = (f32x4){0.f, 0.f, 0.f, 0.f};

    gemm_core_pf128(xb + (size_t)m0 * DIM, B + (size_t)n0 * DIM, SH, SH + 12288, tid, acc);

    // ---- bounce epilogue: full 128x128 bf16 tile in SH (32 KB) ----
    __syncthreads();                              // main-loop reads done
    const int w = tid >> 6, l = tid & 63;
    const int wm = (w >> 1) * 64, wn = (w & 1) * 64;
    const int er = l >> 4, ec = l & 15;
    #pragma unroll
    for (int j = 0; j < 4; ++j) {
        const int colv = wn + j * 16 + ec;
        const float bb = bias[n0 + colv];
        const int cg = colv >> 3, cl = colv & 7;
        #pragma unroll
        for (int i = 0; i < 4; ++i)
            #pragma unroll
            for (int r = 0; r < 4; ++r) {
                const int row = wm + i * 16 + er * 4 + r;
                const int g = ((row >> 2) & 3) << 1;
                SH[row * 128 + ((cg ^ g) << 3) + cl] = f2bf((acc[i][j][r] + bb) * scale);
            }
    }
    __syncthreads();
    {
        const int cg = tid & 15, rr = tid >> 4;
        #pragma unroll
        for (int pass = 0; pass < 8; ++pass) {
            const int row = rr + (pass << 4);
            const int g = ((row >> 2) & 3) << 1;
            uint4 v = *(const uint4*)(SH + row * 128 + ((cg ^ g) << 3));
            *(uint4*)(C + (size_t)(m0 + row) * DIM + n0 + (cg << 3)) = v;
        }
    }
}

// ---------------------------------------------------------------------------
// MLP GEMMs: 64x128 tile, grid (64 m-tiles, 8 n-tiles) = 512 blocks =
// 2 blocks/CU, 256 threads. mode 1: gelu -> bf16 (16 KiB bounce).
// mode 2: +bias +x +attn -> fp32 (two 32-row fp32 bounce rounds).
// ---------------------------------------------------------------------------
__global__ __launch_bounds__(256, 2)
void gemm_bf16(const u16* __restrict__ A, const u16* __restrict__ B,
               const float* __restrict__ bias,
               u16* __restrict__ Cb, float* __restrict__ Cf,
               const float* __restrict__ rx, const u16* __restrict__ rattn,
               int mode)
{
    __shared__ __align__(16) u16 SH[24576];      // As=SH[0..8191], Bs=SH[8192..24575]
    const int tid = threadIdx.x;
    const int m0 = blockIdx.x * 64, n0 = blockIdx.y * 128;

    f32x4 acc[2][4];
    #pragma unroll
    for (int i = 0; i < 2; ++i)
        #pragma unroll
        for (int j = 0; j < 4; ++j) acc[i][j] = (f32x4){0.f, 0.f, 0.f, 0.f};

    gemm_core_pf64(A + (size_t)m0 * DIM, B + (size_t)n0 * DIM, SH, SH + 8192, tid, acc);

    const int w = tid >> 6, l = tid & 63;
    const int wm = (w >> 1) * 32, wn = (w & 1) * 64;
    const int er = l >> 4, ec = l & 15;

    if (mode == 1) {
        // ---- bf16 bounce: 64x128 tile (16 KB) ----
        __syncthreads();
        #pragma unroll
        for (int j = 0; j < 4; ++j) {
            const int colv = wn + j * 16 + ec;
            const float bb = bias[n0 + colv];
            const int cg = colv >> 3, cl = colv & 7;
            #pragma unroll
            for (int i = 0; i < 2; ++i)
                #pragma unroll
                for (int r = 0; r < 4; ++r) {
                    const int row = wm + i * 16 + er * 4 + r;
                    const int g = ((row >> 2) & 3) << 1;
                    float v = acc[i][j][r] + bb;
                    v = 0.5f * v * (1.0f + erff(v * 0.70710678118654752f));
                    SH[row * 128 + ((cg ^ g) << 3) + cl] = f2bf(v);
                }
        }
        __syncthreads();
        const int cg = tid & 15, rr = tid >> 4;
        #pragma unroll
        for (int pass = 0; pass < 4; ++pass) {
            const int row = rr + (pass << 4);
            const int g = ((row >> 2) & 3) << 1;
            uint4 v = *(const uint4*)(SH + row * 128 + ((cg ^ g) << 3));
            *(uint4*)(Cb + (size_t)(m0 + row) * DIM + n0 + (cg << 3)) = v;
        }
    } else {
        // ---- fp32 bounce in 2 half-tiles of 32x128 (16 KB each) ----
        float* SHF = (float*)SH;
        #pragma unroll
        for (int h = 0; h < 2; ++h) {
            __syncthreads();
            if ((w >> 1) == h) {                  // waves owning rows 32h..32h+31
                #pragma unroll
                for (int j = 0; j < 4; ++j) {
                    const int colv = wn + j * 16 + ec;
                    const float bb = bias[n0 + colv];
                    const int c4 = colv >> 2, c2 = colv & 3;
                    #pragma unroll
                    for (int i = 0; i < 2; ++i)
                        #pragma unroll
                        for (int r = 0; r < 4; ++r) {
                            const int rl = i * 16 + er * 4 + r;      // 0..31
                            const int g4 = ((rl >> 2) & 1) << 2;
                            SHF[rl * 128 + ((c4 ^ g4) << 2) + c2] = acc[i][j][r] + bb;
                        }
                }
            }
            __syncthreads();
            const int c4 = tid & 31, rr = tid >> 5;                  // 0..7
            #pragma unroll
            for (int pass = 0; pass < 4; ++pass) {
                const int rl = rr + (pass << 3);
                const int g4 = ((rl >> 2) & 1) << 2;
                float4 v = *(const float4*)(SHF + rl * 128 + ((c4 ^ g4) << 2));
                const size_t idx = (size_t)(m0 + 32 * h + rl) * DIM + n0 + (c4 << 2);
                float4 rxv = *(const float4*)(rx + idx);
                ushort4 rav = *(const ushort4*)(rattn + idx);
                float4 o = { v.x + rxv.x + bf2f(rav.x),
                             v.y + rxv.y + bf2f(rav.y),
                             v.z + rxv.z + bf2f(rav.z),
                             v.w + rxv.w + bf2f(rav.w) };
                *(float4*)(Cf + idx) = o;
            }
        }
    }
}

// ---------------------------------------------------------------------------
// ktv via MFMA, no atomics. grid 256 = 32 (b,h) x 8 s-splits, 256 threads.
// ---------------------------------------------------------------------------
__global__ __launch_bounds__(256)
void ktv_mfma(const u16* __restrict__ Kb, const u16* __restrict__ Vb,
              float* __restrict__ part)
{
    __shared__ u16 Kt[64 * 264];
    __shared__ u16 Vt[64 * 264];
    const int tid = threadIdx.x;
    const int bh = blockIdx.x & 31;
    const int sp = blockIdx.x >> 5;
    const int b = bh >> 4, h = bh & 15;
    const size_t base = (size_t)b * SEQ * DIM + (size_t)h * HDIM + (size_t)sp * 256 * DIM;

    const int dg = (tid & 15) * 4;
    #pragma unroll
    for (int pass = 0; pass < 16; ++pass) {
        const int s = (tid >> 4) + 16 * pass;
        ushort4 kv = *(const ushort4*)(Kb + base + (size_t)s * DIM + dg);
        ushort4 vv = *(const ushort4*)(Vb + base + (size_t)s * DIM + dg);
        Kt[(dg + 0) * 264 + s] = kv.x; Kt[(dg + 1) * 264 + s] = kv.y;
        Kt[(dg + 2) * 264 + s] = kv.z; Kt[(dg + 3) * 264 + s] = kv.w;
        Vt[(dg + 0) * 264 + s] = vv.x; Vt[(dg + 1) * 264 + s] = vv.y;
        Vt[(dg + 2) * 264 + s] = vv.z; Vt[(dg + 3) * 264 + s] = vv.w;
    }
    __syncthreads();

    const int w = tid >> 6, l = tid & 63;
    const int lr = l & 15, kq = l >> 4;
    f32x4 acc[4];
    #pragma unroll
    for (int j = 0; j < 4; ++j) acc[j] = (f32x4){0.f, 0.f, 0.f, 0.f};

    for (int k0 = 0; k0 < 256; k0 += 32) {
        s16x8 af = *(const s16x8*)(Kt + (w * 16 + lr) * 264 + k0 + kq * 8);
        #pragma unroll
        for (int j = 0; j < 4; ++j) {
            s16x8 bf = *(const s16x8*)(Vt + (j * 16 + lr) * 264 + k0 + kq * 8);
            acc[j] = __builtin_amdgcn_mfma_f32_16x16x32_bf16(af, bf, acc[j], 0, 0, 0);
        }
    }

    float* dst = part + ((size_t)sp * 32 + bh) * (HDIM * HDIM);
    const int er = l >> 4, ec = l & 15;
    #pragma unroll
    for (int j = 0; j < 4; ++j)
        #pragma unroll
        for (int r = 0; r < 4; ++r)
            dst[(w * 16 + er * 4 + r) * HDIM + j * 16 + ec] = acc[j][r];
}

// ---------------------------------------------------------------------------
// attn = Q @ KtV (block-diag per head), fused partial-reduction.
// ---------------------------------------------------------------------------
__global__ __launch_bounds__(256)
void qktv_kernel(const u16* __restrict__ Qb, const float* __restrict__ part,
                 u16* __restrict__ attnb)
{
    __shared__ float KV[HDIM * HDIM];
    __shared__ u16 Qs[128 * 68];
    const int tid = threadIdx.x;
    const int h  = blockIdx.x;
    const int mt = blockIdx.y;
    const int row0 = mt * 128;
    const int b = row0 >> 11;
    const int bh = b * NHEAD + h;

    for (int i = tid; i < HDIM * HDIM; i += 256) {
        float s = 0.f;
        #pragma unroll
        for (int sp = 0; sp < NSPLIT; ++sp)
            s += part[((size_t)sp * 32 + bh) * (HDIM * HDIM) + i];
        KV[i] = s;
    }
    const int dg = (tid & 15) * 4;
    #pragma unroll
    for (int pass = 0; pass < 8; ++pass) {
        const int r = (tid >> 4) + 16 * pass;
        ushort4 q = *(const ushort4*)(Qb + (size_t)(row0 + r) * DIM + h * HDIM + dg);
        *(ushort4*)(Qs + r * 68 + dg) = q;
    }
    __syncthreads();

    const int tr = tid >> 3, tc = tid & 7;
    const int r0 = tr * 4, c0 = tc * 8;
    float acc[4][8] = {};
    for (int d = 0; d < HDIM; ++d) {
        float4 ka  = *(const float4*)&KV[d * HDIM + c0];
        float4 kb2 = *(const float4*)&KV[d * HDIM + c0 + 4];
        const float* k8a = (const float*)&ka;
        const float* k8b = (const float*)&kb2;
        float qv[4];
        #pragma unroll
        for (int i = 0; i < 4; ++i) qv[i] = bf2f(Qs[(r0 + i) * 68 + d]);
        #pragma unroll
        for (int i = 0; i < 4; ++i)
            #pragma unroll
            for (int j = 0; j < 4; ++j) {
                acc[i][j]     += qv[i] * k8a[j];
                acc[i][j + 4] += qv[i] * k8b[j];
            }
    }
    #pragma unroll
    for (int i = 0; i < 4; ++i) {
        u16* dst = attnb + (size_t)(row0 + r0 + i) * DIM + h * HDIM + c0;
        ushort4 o0 = { f2bf(acc[i][0]), f2bf(acc[i][1]), f2bf(acc[i][2]), f2bf(acc[i][3]) };
        ushort4 o1 = { f2bf(acc[i][4]), f2bf(acc[i][5]), f2bf(acc[i][6]), f2bf(acc[i][7]) };
        *(ushort4*)(dst)     = o0;
        *(ushort4*)(dst + 4) = o1;
    }
}

// ---------------------------------------------------------------------------
extern "C" void kernel_launch(void* const* d_in, const int* in_sizes, int n_in,
                              void* d_out, int out_size, void* d_ws, size_t ws_size,
                              hipStream_t stream)
{
    const float* x  = (const float*)d_in[0];
    const float* Wq = (const float*)d_in[1];
    const float* bq = (const float*)d_in[2];
    const float* Wk = (const float*)d_in[3];
    const float* bk = (const float*)d_in[4];
    const float* Wv = (const float*)d_in[5];
    const float* bv = (const float*)d_in[6];
    const float* W1 = (const float*)d_in[7];
    const float* b1 = (const float*)d_in[8];
    const float* W2 = (const float*)d_in[9];
    const float* b2 = (const float*)d_in[10];
    float* out = (float*)d_out;

    char* ws = (char*)d_ws;
    const size_t MB = 1u << 20;
    u16* xb   = (u16*)(ws);              //  8 MB
    u16* Wqb  = (u16*)(ws +  8 * MB);    //  2 MB each
    u16* Wkb  = (u16*)(ws + 10 * MB);
    u16* Wvb  = (u16*)(ws + 12 * MB);
    u16* W1b  = (u16*)(ws + 14 * MB);
    u16* W2b  = (u16*)(ws + 16 * MB);
    u16* qb   = (u16*)(ws + 18 * MB);    //  8 MB
    u16* kb   = (u16*)(ws + 26 * MB);    //  8 MB
    u16* vb   = (u16*)(ws + 34 * MB);    //  8 MB
    float* part = (float*)(ws + 42 * MB);//  4 MB
    u16* attnb = kb;
    u16* h1b   = vb;

    pack_all<<<4096 + 5 * 1024, 256, 0, stream>>>(x, Wq, Wk, Wv, W1, W2,
                                                  xb, Wqb, Wkb, Wvb, W1b, W2b);

    qkv_gemm<<<dim3(32, 24), 256, 0, stream>>>(xb, Wqb, Wkb, Wvb, bq, bk, bv, qb, kb, vb);

    ktv_mfma<<<NSPLIT * 32, 256, 0, stream>>>(kb, vb, part);
    qktv_kernel<<<dim3(NHEAD, MROWS / 128), 256, 0, stream>>>(qb, part, attnb);

    gemm_bf16<<<dim3(64, 8), 256, 0, stream>>>(attnb, W1b, b1, h1b, nullptr, nullptr, nullptr, 1);
    gemm_bf16<<<dim3(64, 8), 256, 0, stream>>>(h1b, W2b, b2, nullptr, out, x, attnb, 2);
}

// Round 11
// 195.020 us; speedup vs baseline: 1.0041x; 1.0041x over previous
//
#include <hip/hip_runtime.h>
#include <math.h>

#define DIM    1024
#define BATCH  2
#define SEQ    2048
#define NHEAD  16
#define HDIM   64
#define MROWS  (BATCH*SEQ)   // 4096
#define NSPLIT 8             // ktv S-splits

typedef unsigned short u16;
typedef __attribute__((ext_vector_type(8))) short  s16x8;   // 8 bf16 = 4 VGPRs
typedef __attribute__((ext_vector_type(4))) float  f32x4;

__device__ __forceinline__ float bf2f(u16 h) {
    unsigned u = ((unsigned)h) << 16; float f; __builtin_memcpy(&f, &u, 4); return f;
}
__device__ __forceinline__ u16 f2bf(float f) {
    unsigned u; __builtin_memcpy(&u, &f, 4);
    u += 0x7FFFu + ((u >> 16) & 1u);           // round-to-nearest-even
    return (u16)(u >> 16);
}

// async global->LDS DMA, 16B per lane. LDS dest is wave-uniform base + lane*16.
__device__ __forceinline__ void glds16(const u16* g, u16* l) {
    __builtin_amdgcn_global_load_lds(
        (const __attribute__((address_space(1))) void*)g,
        (__attribute__((address_space(3))) void*)l, 16, 0, 0);
}

// ---------------------------------------------------------------------------
// Fused fp32->bf16 pack for x + 5 weights. One launch.
// ---------------------------------------------------------------------------
__global__ __launch_bounds__(256)
void pack_all(const float* __restrict__ x,
              const float* __restrict__ Wq, const float* __restrict__ Wk,
              const float* __restrict__ Wv, const float* __restrict__ W1,
              const float* __restrict__ W2,
              u16* __restrict__ xb, u16* __restrict__ Wqb, u16* __restrict__ Wkb,
              u16* __restrict__ Wvb, u16* __restrict__ W1b, u16* __restrict__ W2b)
{
    const int bid = blockIdx.x;
    const float* src; u16* dst; int i;
    if (bid < 4096) { src = x; dst = xb; i = bid * 256 + threadIdx.x; }
    else {
        const int w = (bid - 4096) >> 10;
        const int lb = (bid - 4096) & 1023;
        src = (w == 0) ? Wq : (w == 1) ? Wk : (w == 2) ? Wv : (w == 3) ? W1 : W2;
        dst = (w == 0) ? Wqb : (w == 1) ? Wkb : (w == 2) ? Wvb : (w == 3) ? W1b : W2b;
        i = lb * 256 + threadIdx.x;
    }
    float4 v = ((const float4*)src)[i];
    ushort4 o = { f2bf(v.x), f2bf(v.y), f2bf(v.z), f2bf(v.w) };
    ((ushort4*)dst)[i] = o;
}

// ---------------------------------------------------------------------------
// GEMM core, tile 128x128, BK=32, 256 thr = 4 waves (2x2), wave tile 64x64.
// T4 counted-vmcnt pipeline: THREE LDS buffers (48 KiB), prefetch depth 2.
// Per iter: wait vmcnt(4) -> s_barrier -> issue tile it+2 -> compute tile it.
// ---------------------------------------------------------------------------
__device__ __forceinline__ void gemm_core_pf128(const u16* __restrict__ Ab,
                                                const u16* __restrict__ Bb,
                                                u16* As, u16* Bs,  // each 3*4096 u16
                                                int tid, f32x4 acc[4][4])
{
    const int w = tid >> 6, l = tid & 63;
    const int wm = (w >> 1) * 64, wn = (w & 1) * 64;
    const int lr = l & 15, kq = l >> 4;

    // staging: wave w covers rows w*16..w*16+15 (4 lanes x 8 u16 per row)
    const int srow = w * 16 + (l >> 2);
    const int scol = (l & 3) * 8;
    const u16* gA = Ab + (size_t)srow * DIM + scol;
    const u16* gB = Bb + (size_t)srow * DIM + scol;
    const int sdst = w * 512;                  // u16 units (wave-uniform)

    // prologue: tile0 -> buf0, tile1 -> buf1 (8 loads in flight)
    glds16(gA,      As + sdst);         glds16(gA + 64 * DIM,      As + 2048 + sdst);
    glds16(gB,      Bs + sdst);         glds16(gB + 64 * DIM,      Bs + 2048 + sdst);
    glds16(gA + 32, As + 4096 + sdst);  glds16(gA + 32 + 64 * DIM, As + 4096 + 2048 + sdst);
    glds16(gB + 32, Bs + 4096 + sdst);  glds16(gB + 32 + 64 * DIM, Bs + 4096 + 2048 + sdst);

    const int NIT = DIM / 32;
    int cur = 0, nxt2 = 2;
    for (int it = 0; it < NIT; ++it) {
        if (it < NIT - 1) { asm volatile("s_waitcnt vmcnt(4)" ::: "memory"); }
        else              { asm volatile("s_waitcnt vmcnt(0)" ::: "memory"); }
        __builtin_amdgcn_s_barrier();
        asm volatile("" ::: "memory");
        if (it + 2 < NIT) {                    // issue tile it+2 -> buf nxt2
            const int k = (it + 2) * 32;
            u16* An = As + nxt2 * 4096 + sdst;
            u16* Bn = Bs + nxt2 * 4096 + sdst;
            glds16(gA + k, An);  glds16(gA + k + 64 * DIM, An + 2048);
            glds16(gB + k, Bn);  glds16(gB + k + 64 * DIM, Bn + 2048);
        }
        const u16* Ac = As + cur * 4096;
        const u16* Bc = Bs + cur * 4096;
        s16x8 af[4], bfr[4];
        #pragma unroll
        for (int i = 0; i < 4; ++i)
            af[i]  = *(const s16x8*)(Ac + (wm + i * 16 + lr) * 32 + kq * 8);
        #pragma unroll
        for (int j = 0; j < 4; ++j)
            bfr[j] = *(const s16x8*)(Bc + (wn + j * 16 + lr) * 32 + kq * 8);
        __builtin_amdgcn_s_setprio(1);
        #pragma unroll
        for (int i = 0; i < 4; ++i)
            #pragma unroll
            for (int j = 0; j < 4; ++j)
                acc[i][j] = __builtin_amdgcn_mfma_f32_16x16x32_bf16(af[i], bfr[j], acc[i][j], 0, 0, 0);
        __builtin_amdgcn_s_setprio(0);
        cur  = (cur  == 2) ? 0 : cur  + 1;
        nxt2 = (nxt2 == 2) ? 0 : nxt2 + 1;
    }
}

// ---------------------------------------------------------------------------
// MLP core, tile 64x64, BK=32, 4 waves (2m x 2n), wave tile 32x32.
// T4 3-buffer counted-vmcnt, depth 2: 2 glds16/iter -> vmcnt(2).
// LDS 3*(2048+2048) u16 = 24 KiB -> 4 blocks/CU (16 waves/CU, 4/SIMD):
// four independent barrier domains per CU hide each other's stalls
// (round-8/9/10 lesson: these small GEMMs are stall-bound, not pipe-bound).
// ---------------------------------------------------------------------------
__device__ __forceinline__ void gemm_core_64(const u16* __restrict__ Ab,
                                             const u16* __restrict__ Bb,
                                             u16* As /*3*2048*/, u16* Bs /*3*2048*/,
                                             int tid, f32x4 acc[2][2])
{
    const int w  = tid >> 6, l = tid & 63;
    const int wm = (w >> 1) * 32, wn = (w & 1) * 32;
    const int lr = l & 15, kq = l >> 4;

    const int srow = w * 16 + (l >> 2);
    const int scol = (l & 3) * 8;
    const u16* gA = Ab + (size_t)srow * DIM + scol;
    const u16* gB = Bb + (size_t)srow * DIM + scol;
    const int sdst = w * 512;

    // prologue: tile0 -> buf0, tile1 -> buf1 (4 loads in flight)
    glds16(gA,      As + sdst);         glds16(gB,      Bs + sdst);
    glds16(gA + 32, As + 2048 + sdst);  glds16(gB + 32, Bs + 2048 + sdst);

    const int NIT = DIM / 32;
    int cur = 0, nxt2 = 2;
    for (int it = 0; it < NIT; ++it) {
        if (it < NIT - 1) { asm volatile("s_waitcnt vmcnt(2)" ::: "memory"); }
        else              { asm volatile("s_waitcnt vmcnt(0)" ::: "memory"); }
        __builtin_amdgcn_s_barrier();
        asm volatile("" ::: "memory");
        if (it + 2 < NIT) {                    // issue tile it+2 -> buf nxt2
            const int k = (it + 2) * 32;
            glds16(gA + k, As + nxt2 * 2048 + sdst);
            glds16(gB + k, Bs + nxt2 * 2048 + sdst);
        }
        const u16* Ac = As + cur * 2048;
        const u16* Bc = Bs + cur * 2048;
        s16x8 af[2], bfr[2];
        #pragma unroll
        for (int i = 0; i < 2; ++i)
            af[i]  = *(const s16x8*)(Ac + (wm + i * 16 + lr) * 32 + kq * 8);
        #pragma unroll
        for (int j = 0; j < 2; ++j)
            bfr[j] = *(const s16x8*)(Bc + (wn + j * 16 + lr) * 32 + kq * 8);
        __builtin_amdgcn_s_setprio(1);
        #pragma unroll
        for (int i = 0; i < 2; ++i)
            #pragma unroll
            for (int j = 0; j < 2; ++j)
                acc[i][j] = __builtin_amdgcn_mfma_f32_16x16x32_bf16(af[i], bfr[j], acc[i][j], 0, 0, 0);
        __builtin_amdgcn_s_setprio(0);
        cur  = (cur  == 2) ? 0 : cur  + 1;
        nxt2 = (nxt2 == 2) ? 0 : nxt2 + 1;
    }
}

// ---------------------------------------------------------------------------
// Fused QKV projection: grid (32 m-tiles, 24 sel*n-tiles), 256 threads.
// Epilogue: XOR-swizzled LDS bounce -> coalesced dwordx4 stores.
// ---------------------------------------------------------------------------
__global__ __launch_bounds__(256)
void qkv_gemm(const u16* __restrict__ xb,
              const u16* __restrict__ Wq, const u16* __restrict__ Wk, const u16* __restrict__ Wv,
              const float* __restrict__ bq, const float* __restrict__ bk, const float* __restrict__ bv,
              u16* __restrict__ qo, u16* __restrict__ ko, u16* __restrict__ vo)
{
    __shared__ __align__(16) u16 SH[24576];      // loop: As=SH[0..12287], Bs=SH[12288..]
    const int tid = threadIdx.x;
    const int m0  = blockIdx.x * 128;
    const int sel = blockIdx.y >> 3;
    const int n0  = (blockIdx.y & 7) * 128;
    const u16*   B    = (sel == 0) ? Wq : (sel == 1) ? Wk : Wv;
    const float* bias = (sel == 0) ? bq : (sel == 1) ? bk : bv;
    u16*         C    = (sel == 0) ? qo : (sel == 1) ? ko : vo;
    const float scale = (sel == 0) ? 0.125f : 1.0f;

    f32x4 acc[4][4];
    #pragma unroll
    for (int i = 0; i < 4; ++i)
        #pragma unroll
        for (int j = 0; j < 4; ++j) acc[i][j] = (f32x4){0.f, 0.f, 0.f, 0.f};

    gemm_core_pf128(xb + (size_t)m0 * DIM, B + (size_t)n0 * DIM, SH, SH + 12288, tid, acc);

    // ---- bounce epilogue: full 128x128 bf16 tile in SH (32 KB) ----
    __syncthreads();                              // main-loop reads done
    const int w = tid >> 6, l = tid & 63;
    const int wm = (w >> 1) * 64, wn = (w & 1) * 64;
    const int er = l >> 4, ec = l & 15;
    #pragma unroll
    for (int j = 0; j < 4; ++j) {
        const int colv = wn + j * 16 + ec;
        const float bb = bias[n0 + colv];
        const int cg = colv >> 3, cl = colv & 7;
        #pragma unroll
        for (int i = 0; i < 4; ++i)
            #pragma unroll
            for (int r = 0; r < 4; ++r) {
                const int row = wm + i * 16 + er * 4 + r;
                const int g = ((row >> 2) & 3) << 1;
                SH[row * 128 + ((cg ^ g) << 3) + cl] = f2bf((acc[i][j][r] + bb) * scale);
            }
    }
    __syncthreads();
    {
        const int cg = tid & 15, rr = tid >> 4;
        #pragma unroll
        for (int pass = 0; pass < 8; ++pass) {
            const int row = rr + (pass << 4);
            const int g = ((row >> 2) & 3) << 1;
            uint4 v = *(const uint4*)(SH + row * 128 + ((cg ^ g) << 3));
            *(uint4*)(C + (size_t)(m0 + row) * DIM + n0 + (cg << 3)) = v;
        }
    }
}

// ---------------------------------------------------------------------------
// MLP GEMMs: 64x64 tile, grid (64 m-tiles, 16 n-tiles) = 1024 blocks =
// 4 blocks/CU, 256 threads. mode 1: gelu -> bf16 (8 KiB bounce).
// mode 2: +bias +x +attn -> fp32 (single 16 KiB fp32 bounce).
// ---------------------------------------------------------------------------
__global__ __launch_bounds__(256, 4)
void gemm_bf16(const u16* __restrict__ A, const u16* __restrict__ B,
               const float* __restrict__ bias,
               u16* __restrict__ Cb, float* __restrict__ Cf,
               const float* __restrict__ rx, const u16* __restrict__ rattn,
               int mode)
{
    __shared__ __align__(16) u16 SH[12288];      // As=SH[0..6143], Bs=SH[6144..12287]
    const int tid = threadIdx.x;
    const int m0 = blockIdx.x * 64, n0 = blockIdx.y * 64;

    f32x4 acc[2][2];
    #pragma unroll
    for (int i = 0; i < 2; ++i)
        #pragma unroll
        for (int j = 0; j < 2; ++j) acc[i][j] = (f32x4){0.f, 0.f, 0.f, 0.f};

    gemm_core_64(A + (size_t)m0 * DIM, B + (size_t)n0 * DIM, SH, SH + 6144, tid, acc);

    const int w = tid >> 6, l = tid & 63;
    const int wm = (w >> 1) * 32, wn = (w & 1) * 32;
    const int er = l >> 4, ec = l & 15;

    if (mode == 1) {
        // ---- bf16 bounce: 64x64 tile (8 KiB), XOR-8 swizzle ----
        __syncthreads();
        #pragma unroll
        for (int j = 0; j < 2; ++j) {
            const int colv = wn + j * 16 + ec;
            const float bb = bias[n0 + colv];
            const int cg = colv >> 3, cl = colv & 7;
            #pragma unroll
            for (int i = 0; i < 2; ++i)
                #pragma unroll
                for (int r = 0; r < 4; ++r) {
                    const int row = wm + i * 16 + er * 4 + r;
                    const int g = (row >> 2) & 7;
                    float v = acc[i][j][r] + bb;
                    v = 0.5f * v * (1.0f + erff(v * 0.70710678118654752f));
                    SH[row * 64 + ((cg ^ g) << 3) + cl] = f2bf(v);
                }
        }
        __syncthreads();
        {
            const int row = tid >> 2, q = tid & 3;
            const int g = (row >> 2) & 7;
            #pragma unroll
            for (int p = 0; p < 2; ++p) {
                const int cgi = q + p * 4;
                uint4 v = *(const uint4*)(SH + row * 64 + ((cgi ^ g) << 3));
                *(uint4*)(Cb + (size_t)(m0 + row) * DIM + n0 + (cgi << 3)) = v;
            }
        }
    } else {
        // ---- fp32 bounce: 64x64 tile (16 KiB), XOR-16 swizzle ----
        __syncthreads();
        float* SHF = (float*)SH;
        #pragma unroll
        for (int j = 0; j < 2; ++j) {
            const int colv = wn + j * 16 + ec;
            const float bb = bias[n0 + colv];
            const int c4 = colv >> 2, c2 = colv & 3;
            #pragma unroll
            for (int i = 0; i < 2; ++i)
                #pragma unroll
                for (int r = 0; r < 4; ++r) {
                    const int row = wm + i * 16 + er * 4 + r;
                    const int g4 = (row >> 2) & 15;
                    SHF[row * 64 + ((c4 ^ g4) << 2) + c2] = acc[i][j][r] + bb;
                }
        }
        __syncthreads();
        {
            const int row = tid >> 2, q = tid & 3;
            const int g4 = (row >> 2) & 15;
            #pragma unroll
            for (int p = 0; p < 4; ++p) {
                const int c4i = q + p * 4;
                float4 v = *(const float4*)(SHF + row * 64 + ((c4i ^ g4) << 2));
                const size_t idx = (size_t)(m0 + row) * DIM + n0 + (c4i << 2);
                float4 rxv = *(const float4*)(rx + idx);
                ushort4 rav = *(const ushort4*)(rattn + idx);
                float4 o = { v.x + rxv.x + bf2f(rav.x),
                             v.y + rxv.y + bf2f(rav.y),
                             v.z + rxv.z + bf2f(rav.z),
                             v.w + rxv.w + bf2f(rav.w) };
                *(float4*)(Cf + idx) = o;
            }
        }
    }
}

// ---------------------------------------------------------------------------
// ktv via MFMA, no atomics. grid 256 = 32 (b,h) x 8 s-splits, 256 threads.
// ---------------------------------------------------------------------------
__global__ __launch_bounds__(256)
void ktv_mfma(const u16* __restrict__ Kb, const u16* __restrict__ Vb,
              float* __restrict__ part)
{
    __shared__ u16 Kt[64 * 264];
    __shared__ u16 Vt[64 * 264];
    const int tid = threadIdx.x;
    const int bh = blockIdx.x & 31;
    const int sp = blockIdx.x >> 5;
    const int b = bh >> 4, h = bh & 15;
    const size_t base = (size_t)b * SEQ * DIM + (size_t)h * HDIM + (size_t)sp * 256 * DIM;

    const int dg = (tid & 15) * 4;
    #pragma unroll
    for (int pass = 0; pass < 16; ++pass) {
        const int s = (tid >> 4) + 16 * pass;
        ushort4 kv = *(const ushort4*)(Kb + base + (size_t)s * DIM + dg);
        ushort4 vv = *(const ushort4*)(Vb + base + (size_t)s * DIM + dg);
        Kt[(dg + 0) * 264 + s] = kv.x; Kt[(dg + 1) * 264 + s] = kv.y;
        Kt[(dg + 2) * 264 + s] = kv.z; Kt[(dg + 3) * 264 + s] = kv.w;
        Vt[(dg + 0) * 264 + s] = vv.x; Vt[(dg + 1) * 264 + s] = vv.y;
        Vt[(dg + 2) * 264 + s] = vv.z; Vt[(dg + 3) * 264 + s] = vv.w;
    }
    __syncthreads();

    const int w = tid >> 6, l = tid & 63;
    const int lr = l & 15, kq = l >> 4;
    f32x4 acc[4];
    #pragma unroll
    for (int j = 0; j < 4; ++j) acc[j] = (f32x4){0.f, 0.f, 0.f, 0.f};

    for (int k0 = 0; k0 < 256; k0 += 32) {
        s16x8 af = *(const s16x8*)(Kt + (w * 16 + lr) * 264 + k0 + kq * 8);
        #pragma unroll
        for (int j = 0; j < 4; ++j) {
            s16x8 bf = *(const s16x8*)(Vt + (j * 16 + lr) * 264 + k0 + kq * 8);
            acc[j] = __builtin_amdgcn_mfma_f32_16x16x32_bf16(af, bf, acc[j], 0, 0, 0);
        }
    }

    float* dst = part + ((size_t)sp * 32 + bh) * (HDIM * HDIM);
    const int er = l >> 4, ec = l & 15;
    #pragma unroll
    for (int j = 0; j < 4; ++j)
        #pragma unroll
        for (int r = 0; r < 4; ++r)
            dst[(w * 16 + er * 4 + r) * HDIM + j * 16 + ec] = acc[j][r];
}

// ---------------------------------------------------------------------------
// attn = Q @ KtV (block-diag per head), fused partial-reduction.
// ---------------------------------------------------------------------------
__global__ __launch_bounds__(256)
void qktv_kernel(const u16* __restrict__ Qb, const float* __restrict__ part,
                 u16* __restrict__ attnb)
{
    __shared__ float KV[HDIM * HDIM];
    __shared__ u16 Qs[128 * 68];
    const int tid = threadIdx.x;
    const int h  = blockIdx.x;
    const int mt = blockIdx.y;
    const int row0 = mt * 128;
    const int b = row0 >> 11;
    const int bh = b * NHEAD + h;

    for (int i = tid; i < HDIM * HDIM; i += 256) {
        float s = 0.f;
        #pragma unroll
        for (int sp = 0; sp < NSPLIT; ++sp)
            s += part[((size_t)sp * 32 + bh) * (HDIM * HDIM) + i];
        KV[i] = s;
    }
    const int dg = (tid & 15) * 4;
    #pragma unroll
    for (int pass = 0; pass < 8; ++pass) {
        const int r = (tid >> 4) + 16 * pass;
        ushort4 q = *(const ushort4*)(Qb + (size_t)(row0 + r) * DIM + h * HDIM + dg);
        *(ushort4*)(Qs + r * 68 + dg) = q;
    }
    __syncthreads();

    const int tr = tid >> 3, tc = tid & 7;
    const int r0 = tr * 4, c0 = tc * 8;
    float acc[4][8] = {};
    for (int d = 0; d < HDIM; ++d) {
        float4 ka  = *(const float4*)&KV[d * HDIM + c0];
        float4 kb2 = *(const float4*)&KV[d * HDIM + c0 + 4];
        const float* k8a = (const float*)&ka;
        const float* k8b = (const float*)&kb2;
        float qv[4];
        #pragma unroll
        for (int i = 0; i < 4; ++i) qv[i] = bf2f(Qs[(r0 + i) * 68 + d]);
        #pragma unroll
        for (int i = 0; i < 4; ++i)
            #pragma unroll
            for (int j = 0; j < 4; ++j) {
                acc[i][j]     += qv[i] * k8a[j];
                acc[i][j + 4] += qv[i] * k8b[j];
            }
    }
    #pragma unroll
    for (int i = 0; i < 4; ++i) {
        u16* dst = attnb + (size_t)(row0 + r0 + i) * DIM + h * HDIM + c0;
        ushort4 o0 = { f2bf(acc[i][0]), f2bf(acc[i][1]), f2bf(acc[i][2]), f2bf(acc[i][3]) };
        ushort4 o1 = { f2bf(acc[i][4]), f2bf(acc[i][5]), f2bf(acc[i][6]), f2bf(acc[i][7]) };
        *(ushort4*)(dst)     = o0;
        *(ushort4*)(dst + 4) = o1;
    }
}

// ---------------------------------------------------------------------------
extern "C" void kernel_launch(void* const* d_in, const int* in_sizes, int n_in,
                              void* d_out, int out_size, void* d_ws, size_t ws_size,
                              hipStream_t stream)
{
    const float* x  = (const float*)d_in[0];
    const float* Wq = (const float*)d_in[1];
    const float* bq = (const float*)d_in[2];
    const float* Wk = (const float*)d_in[3];
    const float* bk = (const float*)d_in[4];
    const float* Wv = (const float*)d_in[5];
    const float* bv = (const float*)d_in[6];
    const float* W1 = (const float*)d_in[7];
    const float* b1 = (const float*)d_in[8];
    const float* W2 = (const float*)d_in[9];
    const float* b2 = (const float*)d_in[10];
    float* out = (float*)d_out;

    char* ws = (char*)d_ws;
    const size_t MB = 1u << 20;
    u16* xb   = (u16*)(ws);              //  8 MB
    u16* Wqb  = (u16*)(ws +  8 * MB);    //  2 MB each
    u16* Wkb  = (u16*)(ws + 10 * MB);
    u16* Wvb  = (u16*)(ws + 12 * MB);
    u16* W1b  = (u16*)(ws + 14 * MB);
    u16* W2b  = (u16*)(ws + 16 * MB);
    u16* qb   = (u16*)(ws + 18 * MB);    //  8 MB
    u16* kb   = (u16*)(ws + 26 * MB);    //  8 MB
    u16* vb   = (u16*)(ws + 34 * MB);    //  8 MB
    float* part = (float*)(ws + 42 * MB);//  4 MB
    u16* attnb = kb;
    u16* h1b   = vb;

    pack_all<<<4096 + 5 * 1024, 256, 0, stream>>>(x, Wq, Wk, Wv, W1, W2,
                                                  xb, Wqb, Wkb, Wvb, W1b, W2b);

    qkv_gemm<<<dim3(32, 24), 256, 0, stream>>>(xb, Wqb, Wkb, Wvb, bq, bk, bv, qb, kb, vb);

    ktv_mfma<<<NSPLIT * 32, 256, 0, stream>>>(kb, vb, part);
    qktv_kernel<<<dim3(NHEAD, MROWS / 128), 256, 0, stream>>>(qb, part, attnb);

    gemm_bf16<<<dim3(64, 16), 256, 0, stream>>>(attnb, W1b, b1, h1b, nullptr, nullptr, nullptr, 1);
    gemm_bf16<<<dim3(64, 16), 256, 0, stream>>>(h1b, W2b, b2, nullptr, out, x, attnb, 2);
}

// Round 12
// 189.850 us; speedup vs baseline: 1.0315x; 1.0272x over previous
//
#include <hip/hip_runtime.h>
#include <math.h>

#define DIM    1024
#define BATCH  2
#define SEQ    2048
#define NHEAD  16
#define HDIM   64
#define MROWS  (BATCH*SEQ)   // 4096
#define NSPLIT 8             // ktv S-splits

typedef unsigned short u16;
typedef __attribute__((ext_vector_type(8))) short  s16x8;   // 8 bf16 = 4 VGPRs
typedef __attribute__((ext_vector_type(4))) float  f32x4;

__device__ __forceinline__ float bf2f(u16 h) {
    unsigned u = ((unsigned)h) << 16; float f; __builtin_memcpy(&f, &u, 4); return f;
}
__device__ __forceinline__ u16 f2bf(float f) {
    unsigned u; __builtin_memcpy(&u, &f, 4);
    u += 0x7FFFu + ((u >> 16) & 1u);           // round-to-nearest-even
    return (u16)(u >> 16);
}

// async global->LDS DMA, 16B per lane. LDS dest is wave-uniform base + lane*16.
__device__ __forceinline__ void glds16(const u16* g, u16* l) {
    __builtin_amdgcn_global_load_lds(
        (const __attribute__((address_space(1))) void*)g,
        (__attribute__((address_space(3))) void*)l, 16, 0, 0);
}

// ---------------------------------------------------------------------------
// Fused fp32->bf16 pack for x + 5 weights. One launch.
// ---------------------------------------------------------------------------
__global__ __launch_bounds__(256)
void pack_all(const float* __restrict__ x,
              const float* __restrict__ Wq, const float* __restrict__ Wk,
              const float* __restrict__ Wv, const float* __restrict__ W1,
              const float* __restrict__ W2,
              u16* __restrict__ xb, u16* __restrict__ Wqb, u16* __restrict__ Wkb,
              u16* __restrict__ Wvb, u16* __restrict__ W1b, u16* __restrict__ W2b)
{
    const int bid = blockIdx.x;
    const float* src; u16* dst; int i;
    if (bid < 4096) { src = x; dst = xb; i = bid * 256 + threadIdx.x; }
    else {
        const int w = (bid - 4096) >> 10;
        const int lb = (bid - 4096) & 1023;
        src = (w == 0) ? Wq : (w == 1) ? Wk : (w == 2) ? Wv : (w == 3) ? W1 : W2;
        dst = (w == 0) ? Wqb : (w == 1) ? Wkb : (w == 2) ? Wvb : (w == 3) ? W1b : W2b;
        i = lb * 256 + threadIdx.x;
    }
    float4 v = ((const float4*)src)[i];
    ushort4 o = { f2bf(v.x), f2bf(v.y), f2bf(v.z), f2bf(v.w) };
    ((ushort4*)dst)[i] = o;
}

// ---------------------------------------------------------------------------
// GEMM core, tile 128x128, BK=32, 256 thr = 4 waves (2x2), wave tile 64x64.
// T4 counted-vmcnt pipeline: THREE LDS buffers (48 KiB), prefetch depth 2.
// NEW: both-sides XOR granule swizzle (rule #21). LDS granule (row, g) holds
// global granule (row, g ^ ((row>>1)&3)): staging SOURCE col is pre-swizzled
// within the row (coalescing kept — permutation stays inside the 64B row
// segment), glds16 dest stays linear, ds_read applies the same XOR.
// Kills the 8-way row-stride bank conflict on fragment reads (-> 2-way, free).
// ---------------------------------------------------------------------------
__device__ __forceinline__ void gemm_core_pf128(const u16* __restrict__ Ab,
                                                const u16* __restrict__ Bb,
                                                u16* As, u16* Bs,  // each 3*4096 u16
                                                int tid, f32x4 acc[4][4])
{
    const int w = tid >> 6, l = tid & 63;
    const int wm = (w >> 1) * 64, wn = (w & 1) * 64;
    const int lr = l & 15, kq = l >> 4;

    // staging: wave w covers rows w*16..w*16+15 (4 lanes x 8 u16 per row),
    // source granule pre-swizzled: g ^ ((row>>1)&3)
    const int srow = w * 16 + (l >> 2);
    const int scol = (((l & 3) ^ ((srow >> 1) & 3)) << 3);
    const u16* gA = Ab + (size_t)srow * DIM + scol;
    const u16* gB = Bb + (size_t)srow * DIM + scol;
    const int sdst = w * 512;                  // u16 units (wave-uniform)

    // prologue: tile0 -> buf0, tile1 -> buf1 (8 loads in flight)
    glds16(gA,      As + sdst);         glds16(gA + 64 * DIM,      As + 2048 + sdst);
    glds16(gB,      Bs + sdst);         glds16(gB + 64 * DIM,      Bs + 2048 + sdst);
    glds16(gA + 32, As + 4096 + sdst);  glds16(gA + 32 + 64 * DIM, As + 4096 + 2048 + sdst);
    glds16(gB + 32, Bs + 4096 + sdst);  glds16(gB + 32 + 64 * DIM, Bs + 4096 + 2048 + sdst);

    const int NIT = DIM / 32;
    int cur = 0, nxt2 = 2;
    for (int it = 0; it < NIT; ++it) {
        if (it < NIT - 1) { asm volatile("s_waitcnt vmcnt(4)" ::: "memory"); }
        else              { asm volatile("s_waitcnt vmcnt(0)" ::: "memory"); }
        __builtin_amdgcn_s_barrier();
        asm volatile("" ::: "memory");
        if (it + 2 < NIT) {                    // issue tile it+2 -> buf nxt2
            const int k = (it + 2) * 32;
            u16* An = As + nxt2 * 4096 + sdst;
            u16* Bn = Bs + nxt2 * 4096 + sdst;
            glds16(gA + k, An);  glds16(gA + k + 64 * DIM, An + 2048);
            glds16(gB + k, Bn);  glds16(gB + k + 64 * DIM, Bn + 2048);
        }
        const u16* Ac = As + cur * 4096;
        const u16* Bc = Bs + cur * 4096;
        s16x8 af[4], bfr[4];
        #pragma unroll
        for (int i = 0; i < 4; ++i) {
            const int ra = wm + i * 16 + lr;
            af[i]  = *(const s16x8*)(Ac + ra * 32 + ((kq ^ ((ra >> 1) & 3)) << 3));
        }
        #pragma unroll
        for (int j = 0; j < 4; ++j) {
            const int rb = wn + j * 16 + lr;
            bfr[j] = *(const s16x8*)(Bc + rb * 32 + ((kq ^ ((rb >> 1) & 3)) << 3));
        }
        __builtin_amdgcn_s_setprio(1);
        #pragma unroll
        for (int i = 0; i < 4; ++i)
            #pragma unroll
            for (int j = 0; j < 4; ++j)
                acc[i][j] = __builtin_amdgcn_mfma_f32_16x16x32_bf16(af[i], bfr[j], acc[i][j], 0, 0, 0);
        __builtin_amdgcn_s_setprio(0);
        cur  = (cur  == 2) ? 0 : cur  + 1;
        nxt2 = (nxt2 == 2) ? 0 : nxt2 + 1;
    }
}

// ---------------------------------------------------------------------------
// MLP core, tile 64x128, BK=32, 4 waves (2m x 2n), wave tile 32x64.
// T4 3-buffer counted-vmcnt depth 2 (round-9 proven best), same XOR swizzle.
// ---------------------------------------------------------------------------
__device__ __forceinline__ void gemm_core_pf64(const u16* __restrict__ Ab,
                                               const u16* __restrict__ Bb,
                                               u16* As /*3*2048*/, u16* Bs /*3*4096*/,
                                               int tid, f32x4 acc[2][4])
{
    const int w  = tid >> 6, l = tid & 63;
    const int wm = (w >> 1) * 32, wn = (w & 1) * 64;
    const int lr = l & 15, kq = l >> 4;

    const int srow = w * 16 + (l >> 2);
    const int scol = (((l & 3) ^ ((srow >> 1) & 3)) << 3);
    const u16* gA = Ab + (size_t)srow * DIM + scol;
    const u16* gB = Bb + (size_t)srow * DIM + scol;
    const int sdst = w * 512;

    // prologue: tile0 -> buf0, tile1 -> buf1 (6 loads in flight)
    glds16(gA,      As + sdst);
    glds16(gB,      Bs + sdst);        glds16(gB + 64 * DIM,      Bs + 2048 + sdst);
    glds16(gA + 32, As + 2048 + sdst);
    glds16(gB + 32, Bs + 4096 + sdst); glds16(gB + 32 + 64 * DIM, Bs + 4096 + 2048 + sdst);

    const int NIT = DIM / 32;
    int cur = 0, nxt2 = 2;
    for (int it = 0; it < NIT; ++it) {
        if (it < NIT - 1) { asm volatile("s_waitcnt vmcnt(3)" ::: "memory"); }
        else              { asm volatile("s_waitcnt vmcnt(0)" ::: "memory"); }
        __builtin_amdgcn_s_barrier();
        asm volatile("" ::: "memory");
        if (it + 2 < NIT) {                    // issue tile it+2 -> buf nxt2
            const int k = (it + 2) * 32;
            u16* An = As + nxt2 * 2048 + sdst;
            u16* Bn = Bs + nxt2 * 4096 + sdst;
            glds16(gA + k, An);
            glds16(gB + k, Bn);  glds16(gB + k + 64 * DIM, Bn + 2048);
        }
        const u16* Ac = As + cur * 2048;
        const u16* Bc = Bs + cur * 4096;
        s16x8 af[2], bfr[4];
        #pragma unroll
        for (int i = 0; i < 2; ++i) {
            const int ra = wm + i * 16 + lr;
            af[i]  = *(const s16x8*)(Ac + ra * 32 + ((kq ^ ((ra >> 1) & 3)) << 3));
        }
        #pragma unroll
        for (int j = 0; j < 4; ++j) {
            const int rb = wn + j * 16 + lr;
            bfr[j] = *(const s16x8*)(Bc + rb * 32 + ((kq ^ ((rb >> 1) & 3)) << 3));
        }
        __builtin_amdgcn_s_setprio(1);
        #pragma unroll
        for (int i = 0; i < 2; ++i)
            #pragma unroll
            for (int j = 0; j < 4; ++j)
                acc[i][j] = __builtin_amdgcn_mfma_f32_16x16x32_bf16(af[i], bfr[j], acc[i][j], 0, 0, 0);
        __builtin_amdgcn_s_setprio(0);
        cur  = (cur  == 2) ? 0 : cur  + 1;
        nxt2 = (nxt2 == 2) ? 0 : nxt2 + 1;
    }
}

// ---------------------------------------------------------------------------
// Fused QKV projection: grid (32 m-tiles, 24 sel*n-tiles), 256 threads.
// Epilogue: XOR-swizzled LDS bounce -> coalesced dwordx4 stores.
// ---------------------------------------------------------------------------
__global__ __launch_bounds__(256)
void qkv_gemm(const u16* __restrict__ xb,
              const u16* __restrict__ Wq, const u16* __restrict__ Wk, const u16* __restrict__ Wv,
              const float* __restrict__ bq, const float* __restrict__ bk, const float* __restrict__ bv,
              u16* __restrict__ qo, u16* __restrict__ ko, u16* __restrict__ vo)
{
    __shared__ __align__(16) u16 SH[24576];      // loop: As=SH[0..12287], Bs=SH[12288..]
    const int tid = threadIdx.x;
    const int m0  = blockIdx.x * 128;
    const int sel = blockIdx.y >> 3;
    const int n0  = (blockIdx.y & 7) * 128;
    const u16*   B    = (sel == 0) ? Wq : (sel == 1) ? Wk : Wv;
    const float* bias = (sel == 0) ? bq : (sel == 1) ? bk : bv;
    u16*         C    = (sel == 0) ? qo : (sel == 1) ? ko : vo;
    const float scale = (sel == 0) ? 0.125f : 1.0f;

    f32x4 acc[4][4];
    #pragma unroll
    for (int i = 0; i < 4; ++i)
        #pragma unroll
        for (int j = 0; j < 4; ++j) acc[i][j] = (f32x4){0.f, 0.f, 0.f, 0.f};

    gemm_core_pf128(xb + (size_t)m0 * DIM, B + (size_t)n0 * DIM, SH, SH + 12288, tid, acc);

    // ---- bounce epilogue: full 128x128 bf16 tile in SH (32 KB) ----
    __syncthreads();                              // main-loop reads done
    const int w = tid >> 6, l = tid & 63;
    const int wm = (w >> 1) * 64, wn = (w & 1) * 64;
    const int er = l >> 4, ec = l & 15;
    #pragma unroll
    for (int j = 0; j < 4; ++j) {
        const int colv = wn + j * 16 + ec;
        const float bb = bias[n0 + colv];
        const int cg = colv >> 3, cl = colv & 7;
        #pragma unroll
        for (int i = 0; i < 4; ++i)
            #pragma unroll
            for (int r = 0; r < 4; ++r) {
                const int row = wm + i * 16 + er * 4 + r;
                const int g = ((row >> 2) & 3) << 1;
                SH[row * 128 + ((cg ^ g) << 3) + cl] = f2bf((acc[i][j][r] + bb) * scale);
            }
    }
    __syncthreads();
    {
        const int cg = tid & 15, rr = tid >> 4;
        #pragma unroll
        for (int pass = 0; pass < 8; ++pass) {
            const int row = rr + (pass << 4);
            const int g = ((row >> 2) & 3) << 1;
            uint4 v = *(const uint4*)(SH + row * 128 + ((cg ^ g) << 3));
            *(uint4*)(C + (size_t)(m0 + row) * DIM + n0 + (cg << 3)) = v;
        }
    }
}

// ---------------------------------------------------------------------------
// MLP GEMMs: 64x128 tile, grid (64 m-tiles, 8 n-tiles) = 512 blocks =
// 2 blocks/CU, 256 threads. mode 1: gelu -> bf16 (16 KiB bounce).
// mode 2: +bias +x +attn -> fp32 (two 32-row fp32 bounce rounds).
// ---------------------------------------------------------------------------
__global__ __launch_bounds__(256, 2)
void gemm_bf16(const u16* __restrict__ A, const u16* __restrict__ B,
               const float* __restrict__ bias,
               u16* __restrict__ Cb, float* __restrict__ Cf,
               const float* __restrict__ rx, const u16* __restrict__ rattn,
               int mode)
{
    __shared__ __align__(16) u16 SH[18432];      // As=SH[0..6143], Bs=SH[6144..18431]
    const int tid = threadIdx.x;
    const int m0 = blockIdx.x * 64, n0 = blockIdx.y * 128;

    f32x4 acc[2][4];
    #pragma unroll
    for (int i = 0; i < 2; ++i)
        #pragma unroll
        for (int j = 0; j < 4; ++j) acc[i][j] = (f32x4){0.f, 0.f, 0.f, 0.f};

    gemm_core_pf64(A + (size_t)m0 * DIM, B + (size_t)n0 * DIM, SH, SH + 6144, tid, acc);

    const int w = tid >> 6, l = tid & 63;
    const int wm = (w >> 1) * 32, wn = (w & 1) * 64;
    const int er = l >> 4, ec = l & 15;

    if (mode == 1) {
        // ---- bf16 bounce: 64x128 tile (16 KB) ----
        __syncthreads();
        #pragma unroll
        for (int j = 0; j < 4; ++j) {
            const int colv = wn + j * 16 + ec;
            const float bb = bias[n0 + colv];
            const int cg = colv >> 3, cl = colv & 7;
            #pragma unroll
            for (int i = 0; i < 2; ++i)
                #pragma unroll
                for (int r = 0; r < 4; ++r) {
                    const int row = wm + i * 16 + er * 4 + r;
                    const int g = ((row >> 2) & 3) << 1;
                    float v = acc[i][j][r] + bb;
                    v = 0.5f * v * (1.0f + erff(v * 0.70710678118654752f));
                    SH[row * 128 + ((cg ^ g) << 3) + cl] = f2bf(v);
                }
        }
        __syncthreads();
        const int cg = tid & 15, rr = tid >> 4;
        #pragma unroll
        for (int pass = 0; pass < 4; ++pass) {
            const int row = rr + (pass << 4);
            const int g = ((row >> 2) & 3) << 1;
            uint4 v = *(const uint4*)(SH + row * 128 + ((cg ^ g) << 3));
            *(uint4*)(Cb + (size_t)(m0 + row) * DIM + n0 + (cg << 3)) = v;
        }
    } else {
        // ---- fp32 bounce in 2 half-tiles of 32x128 (16 KB each) ----
        float* SHF = (float*)SH;
        #pragma unroll
        for (int h = 0; h < 2; ++h) {
            __syncthreads();
            if ((w >> 1) == h) {                  // waves owning rows 32h..32h+31
                #pragma unroll
                for (int j = 0; j < 4; ++j) {
                    const int colv = wn + j * 16 + ec;
                    const float bb = bias[n0 + colv];
                    const int c4 = colv >> 2, c2 = colv & 3;
                    #pragma unroll
                    for (int i = 0; i < 2; ++i)
                        #pragma unroll
                        for (int r = 0; r < 4; ++r) {
                            const int rl = i * 16 + er * 4 + r;      // 0..31
                            const int g4 = ((rl >> 2) & 1) << 2;
                            SHF[rl * 128 + ((c4 ^ g4) << 2) + c2] = acc[i][j][r] + bb;
                        }
                }
            }
            __syncthreads();
            const int c4 = tid & 31, rr = tid >> 5;                  // 0..7
            #pragma unroll
            for (int pass = 0; pass < 4; ++pass) {
                const int rl = rr + (pass << 3);
                const int g4 = ((rl >> 2) & 1) << 2;
                float4 v = *(const float4*)(SHF + rl * 128 + ((c4 ^ g4) << 2));
                const size_t idx = (size_t)(m0 + 32 * h + rl) * DIM + n0 + (c4 << 2);
                float4 rxv = *(const float4*)(rx + idx);
                ushort4 rav = *(const ushort4*)(rattn + idx);
                float4 o = { v.x + rxv.x + bf2f(rav.x),
                             v.y + rxv.y + bf2f(rav.y),
                             v.z + rxv.z + bf2f(rav.z),
                             v.w + rxv.w + bf2f(rav.w) };
                *(float4*)(Cf + idx) = o;
            }
        }
    }
}

// ---------------------------------------------------------------------------
// ktv via MFMA, no atomics. grid 256 = 32 (b,h) x 8 s-splits, 256 threads.
// ---------------------------------------------------------------------------
__global__ __launch_bounds__(256)
void ktv_mfma(const u16* __restrict__ Kb, const u16* __restrict__ Vb,
              float* __restrict__ part)
{
    __shared__ u16 Kt[64 * 264];
    __shared__ u16 Vt[64 * 264];
    const int tid = threadIdx.x;
    const int bh = blockIdx.x & 31;
    const int sp = blockIdx.x >> 5;
    const int b = bh >> 4, h = bh & 15;
    const size_t base = (size_t)b * SEQ * DIM + (size_t)h * HDIM + (size_t)sp * 256 * DIM;

    const int dg = (tid & 15) * 4;
    #pragma unroll
    for (int pass = 0; pass < 16; ++pass) {
        const int s = (tid >> 4) + 16 * pass;
        ushort4 kv = *(const ushort4*)(Kb + base + (size_t)s * DIM + dg);
        ushort4 vv = *(const ushort4*)(Vb + base + (size_t)s * DIM + dg);
        Kt[(dg + 0) * 264 + s] = kv.x; Kt[(dg + 1) * 264 + s] = kv.y;
        Kt[(dg + 2) * 264 + s] = kv.z; Kt[(dg + 3) * 264 + s] = kv.w;
        Vt[(dg + 0) * 264 + s] = vv.x; Vt[(dg + 1) * 264 + s] = vv.y;
        Vt[(dg + 2) * 264 + s] = vv.z; Vt[(dg + 3) * 264 + s] = vv.w;
    }
    __syncthreads();

    const int w = tid >> 6, l = tid & 63;
    const int lr = l & 15, kq = l >> 4;
    f32x4 acc[4];
    #pragma unroll
    for (int j = 0; j < 4; ++j) acc[j] = (f32x4){0.f, 0.f, 0.f, 0.f};

    for (int k0 = 0; k0 < 256; k0 += 32) {
        s16x8 af = *(const s16x8*)(Kt + (w * 16 + lr) * 264 + k0 + kq * 8);
        #pragma unroll
        for (int j = 0; j < 4; ++j) {
            s16x8 bf = *(const s16x8*)(Vt + (j * 16 + lr) * 264 + k0 + kq * 8);
            acc[j] = __builtin_amdgcn_mfma_f32_16x16x32_bf16(af, bf, acc[j], 0, 0, 0);
        }
    }

    float* dst = part + ((size_t)sp * 32 + bh) * (HDIM * HDIM);
    const int er = l >> 4, ec = l & 15;
    #pragma unroll
    for (int j = 0; j < 4; ++j)
        #pragma unroll
        for (int r = 0; r < 4; ++r)
            dst[(w * 16 + er * 4 + r) * HDIM + j * 16 + ec] = acc[j][r];
}

// ---------------------------------------------------------------------------
// attn = Q @ KtV (block-diag per head), fused partial-reduction.
// ---------------------------------------------------------------------------
__global__ __launch_bounds__(256)
void qktv_kernel(const u16* __restrict__ Qb, const float* __restrict__ part,
                 u16* __restrict__ attnb)
{
    __shared__ float KV[HDIM * HDIM];
    __shared__ u16 Qs[128 * 68];
    const int tid = threadIdx.x;
    const int h  = blockIdx.x;
    const int mt = blockIdx.y;
    const int row0 = mt * 128;
    const int b = row0 >> 11;
    const int bh = b * NHEAD + h;

    for (int i = tid; i < HDIM * HDIM; i += 256) {
        float s = 0.f;
        #pragma unroll
        for (int sp = 0; sp < NSPLIT; ++sp)
            s += part[((size_t)sp * 32 + bh) * (HDIM * HDIM) + i];
        KV[i] = s;
    }
    const int dg = (tid & 15) * 4;
    #pragma unroll
    for (int pass = 0; pass < 8; ++pass) {
        const int r = (tid >> 4) + 16 * pass;
        ushort4 q = *(const ushort4*)(Qb + (size_t)(row0 + r) * DIM + h * HDIM + dg);
        *(ushort4*)(Qs + r * 68 + dg) = q;
    }
    __syncthreads();

    const int tr = tid >> 3, tc = tid & 7;
    const int r0 = tr * 4, c0 = tc * 8;
    float acc[4][8] = {};
    for (int d = 0; d < HDIM; ++d) {
        float4 ka  = *(const float4*)&KV[d * HDIM + c0];
        float4 kb2 = *(const float4*)&KV[d * HDIM + c0 + 4];
        const float* k8a = (const float*)&ka;
        const float* k8b = (const float*)&kb2;
        float qv[4];
        #pragma unroll
        for (int i = 0; i < 4; ++i) qv[i] = bf2f(Qs[(r0 + i) * 68 + d]);
        #pragma unroll
        for (int i = 0; i < 4; ++i)
            #pragma unroll
            for (int j = 0; j < 4; ++j) {
                acc[i][j]     += qv[i] * k8a[j];
                acc[i][j + 4] += qv[i] * k8b[j];
            }
    }
    #pragma unroll
    for (int i = 0; i < 4; ++i) {
        u16* dst = attnb + (size_t)(row0 + r0 + i) * DIM + h * HDIM + c0;
        ushort4 o0 = { f2bf(acc[i][0]), f2bf(acc[i][1]), f2bf(acc[i][2]), f2bf(acc[i][3]) };
        ushort4 o1 = { f2bf(acc[i][4]), f2bf(acc[i][5]), f2bf(acc[i][6]), f2bf(acc[i][7]) };
        *(ushort4*)(dst)     = o0;
        *(ushort4*)(dst + 4) = o1;
    }
}

// ---------------------------------------------------------------------------
extern "C" void kernel_launch(void* const* d_in, const int* in_sizes, int n_in,
                              void* d_out, int out_size, void* d_ws, size_t ws_size,
                              hipStream_t stream)
{
    const float* x  = (const float*)d_in[0];
    const float* Wq = (const float*)d_in[1];
    const float* bq = (const float*)d_in[2];
    const float* Wk = (const float*)d_in[3];
    const float* bk = (const float*)d_in[4];
    const float* Wv = (const float*)d_in[5];
    const float* bv = (const float*)d_in[6];
    const float* W1 = (const float*)d_in[7];
    const float* b1 = (const float*)d_in[8];
    const float* W2 = (const float*)d_in[9];
    const float* b2 = (const float*)d_in[10];
    float* out = (float*)d_out;

    char* ws = (char*)d_ws;
    const size_t MB = 1u << 20;
    u16* xb   = (u16*)(ws);              //  8 MB
    u16* Wqb  = (u16*)(ws +  8 * MB);    //  2 MB each
    u16* Wkb  = (u16*)(ws + 10 * MB);
    u16* Wvb  = (u16*)(ws + 12 * MB);
    u16* W1b  = (u16*)(ws + 14 * MB);
    u16* W2b  = (u16*)(ws + 16 * MB);
    u16* qb   = (u16*)(ws + 18 * MB);    //  8 MB
    u16* kb   = (u16*)(ws + 26 * MB);    //  8 MB
    u16* vb   = (u16*)(ws + 34 * MB);    //  8 MB
    float* part = (float*)(ws + 42 * MB);//  4 MB
    u16* attnb = kb;
    u16* h1b   = vb;

    pack_all<<<4096 + 5 * 1024, 256, 0, stream>>>(x, Wq, Wk, Wv, W1, W2,
                                                  xb, Wqb, Wkb, Wvb, W1b, W2b);

    qkv_gemm<<<dim3(32, 24), 256, 0, stream>>>(xb, Wqb, Wkb, Wvb, bq, bk, bv, qb, kb, vb);

    ktv_mfma<<<NSPLIT * 32, 256, 0, stream>>>(kb, vb, part);
    qktv_kernel<<<dim3(NHEAD, MROWS / 128), 256, 0, stream>>>(qb, part, attnb);

    gemm_bf16<<<dim3(64, 8), 256, 0, stream>>>(attnb, W1b, b1, h1b, nullptr, nullptr, nullptr, 1);
    gemm_bf16<<<dim3(64, 8), 256, 0, stream>>>(h1b, W2b, b2, nullptr, out, x, attnb, 2);
}